// Round 1
// baseline (157.495 us; speedup 1.0000x reference)
//
#include <hip/hip_runtime.h>

#define VZ 128
#define VY 192
#define VX 192
#define NC 8
#define PS 64

struct F4 { float x, y, z, w; };

// Gather kernel: out[c,z,y,x] = sum_over_covering_patches(patch*w) / (1e-20 + sum w).
// Grid start analysis: z starts {0,32,64}, y/x starts {0,32,64,96,128} -> the
// union of patches covers the whole volume, so mask==1 everywhere and the
// up_global term vanishes (where(mask==1, 0, up_global)). We skip it entirely.
__global__ __launch_bounds__(192)
void agg_kernel(const float* __restrict__ patches, float* __restrict__ out)
{
    // 1D separable gaussian table g[d] = exp(-0.5*((d-32)/8)^2), d in [0,64)
    __shared__ float g[PS];
    const int t = threadIdx.y * 48 + threadIdx.x;
    if (t < PS) {
        const float d = ((float)t - 32.0f) * 0.125f;   // (d-32)/8
        g[t] = __expf(-0.5f * d * d);
    }
    __syncthreads();

    const int x0 = threadIdx.x << 2;          // 0,4,...,188
    const int y  = blockIdx.x * 4 + threadIdx.y;
    const int z  = blockIdx.y;
    const int c  = blockIdx.z;

    // Covering patch starts per axis: multiples of 32 with s <= coord < s+64.
    // "high" candidate = floor(coord/32)*32 clamped to the last start;
    // "low" candidate = high-32 if still covering.
    const int szh = min(64,  (z  >> 5) << 5);
    const int szl = szh - 32;
    const bool z2 = (szl >= 0) && ((z - szl) < PS);
    const int syh = min(128, (y  >> 5) << 5);
    const int syl = syh - 32;
    const bool y2 = (syl >= 0) && ((y - syl) < PS);
    const int sxh = min(128, (x0 >> 5) << 5);
    const int sxl = sxh - 32;
    const bool x2 = (sxl >= 0) && ((x0 - sxl) < PS);   // shared by all 4 lanes (4|32)

    // Per-axis gaussian factors (LDS reads; float4 read for the x-vector).
    const F4* g4 = (const F4*)g;
    const F4 wxh = g4[(x0 - sxh) >> 2];
    F4 wxl = {0.f, 0.f, 0.f, 0.f};
    if (x2) wxl = g4[(x0 - sxl) >> 2];
    const float gzh = g[z - szh];
    const float gyh = g[y - syh];
    const float gzl = z2 ? g[z - szl] : 0.0f;
    const float gyl = y2 ? g[y - syl] : 0.0f;

    float a0 = 0.f, a1 = 0.f, a2 = 0.f, a3 = 0.f;
    float w0 = 1e-20f, w1 = 1e-20f, w2 = 1e-20f, w3 = 1e-20f;

#define PROC(SZ, SY, SX, WZY, WX)                                             \
    do {                                                                      \
        const int p = (((SZ) >> 5) * 5 + ((SY) >> 5)) * 5 + ((SX) >> 5);      \
        const size_t off = ((((size_t)(p * NC + c) * PS + (size_t)(z - (SZ))) \
                             * PS + (size_t)(y - (SY)))                       \
                            * PS + (size_t)(x0 - (SX)));                      \
        const F4 pv = *(const F4*)(patches + off);                            \
        const float wzy = (WZY);                                              \
        a0 += pv.x * (wzy * (WX).x);  w0 += wzy * (WX).x;                     \
        a1 += pv.y * (wzy * (WX).y);  w1 += wzy * (WX).y;                     \
        a2 += pv.z * (wzy * (WX).z);  w2 += wzy * (WX).z;                     \
        a3 += pv.w * (wzy * (WX).w);  w3 += wzy * (WX).w;                     \
    } while (0)

    // Fully unrolled over the <=8 covering patches (static control flow).
    PROC(szh, syh, sxh, gzh * gyh, wxh);
    if (x2) PROC(szh, syh, sxl, gzh * gyh, wxl);
    if (y2) {
        PROC(szh, syl, sxh, gzh * gyl, wxh);
        if (x2) PROC(szh, syl, sxl, gzh * gyl, wxl);
    }
    if (z2) {
        PROC(szl, syh, sxh, gzl * gyh, wxh);
        if (x2) PROC(szl, syh, sxl, gzl * gyh, wxl);
        if (y2) {
            PROC(szl, syl, sxh, gzl * gyl, wxh);
            if (x2) PROC(szl, syl, sxl, gzl * gyl, wxl);
        }
    }
#undef PROC

    F4 r;
    r.x = a0 / w0;
    r.y = a1 / w1;
    r.z = a2 / w2;
    r.w = a3 / w3;
    const size_t oidx = (((size_t)c * VZ + z) * VY + y) * VX + x0;
    *(F4*)(out + oidx) = r;
}

extern "C" void kernel_launch(void* const* d_in, const int* in_sizes, int n_in,
                              void* d_out, int out_size, void* d_ws, size_t ws_size,
                              hipStream_t stream) {
    const float* patches = (const float*)d_in[0];
    // d_in[1] (global_logit) unused: mask covers the full volume, so the
    // up_global term is zero everywhere. d_in[2] (starts) is the fixed
    // make_grid_starts() grid, derived analytically in-kernel.
    float* out = (float*)d_out;

    dim3 block(48, 4, 1);            // 192 threads = 3 waves; x-vector of 4 floats
    dim3 grid(VY / 4, VZ, NC);       // y-groups, z, channel
    agg_kernel<<<grid, block, 0, stream>>>(patches, out);
}